// Round 15
// baseline (160.434 us; speedup 1.0000x reference)
//
#include <hip/hip_runtime.h>

#define HH 299
#define WW 299
#define HW (HH * WW)
#define BORDER 3
#define NT 256
#define RPB 12
#define CHUNKS 25            // 12*25 = 300 rows (row 299 dup-clamped)
#define INV299 (1.0f / 299.0f)

typedef float f4 __attribute__((ext_vector_type(4)));
typedef f4 __attribute__((aligned(4))) f4a;   // 4B-aligned float4 loads

__global__ __launch_bounds__(NT) void crop_resize_kernel(
    const float* __restrict__ x,   // (S, 3, H, W)
    const int*   __restrict__ f,   // (S, G, 4)
    float*       __restrict__ out, // (S, G, 3, H, W)
    int G)
{
    __shared__ float sV[RPB][304];   // fused vertical rows, ONE channel, 14.6 KB

    // Bijective XCD swizzle (grid = 38400 = 8 * 4800): contiguous logical
    // chunks per XCD; consecutive blocks share crop+channel planes.
    int cpx = (int)(gridDim.x >> 3);
    int hb  = blockIdx.x;
    int blk = (hb & 7) * cpx + (hb >> 3);

    // blk = (sg*3 + ch)*CHUNKS + chunk : chunk fastest, then channel, then crop.
    int chunk = blk % CHUNKS;
    int sgc   = blk / CHUNKS;            // sg*3 + ch
    int ch    = sgc % 3;
    int sg    = sgc / 3;                 // crop index si*G + gi
    int si    = sg / G;
    int r0    = chunk * RPB;             // first output row of this block

    const int* box = f + (sg << 2);
    int tlx = max(box[0] - BORDER, 0);
    int tly = max(box[1] - BORDER, 0);
    int hc  = min(box[2] + BORDER, HH - 1) - tlx;
    int wc  = min(box[3] + BORDER, WW - 1) - tly;

    int t = threadIdx.x;
    const float* img = x + si * 3 * HW + ch * HW;   // this block's channel plane
    float hstep = (float)hc * INV299;

    // Staging: unit u in [0, RPB*76): r = u/76, quad q. Coords recomputed
    // per unit (no runtime-indexed arrays -> stays in registers).
    #pragma unroll
    for (int pass = 0; pass < 4; ++pass) {
        int u = t + pass * NT;
        if (u < RPB * 76) {
            int r = u / 76;                          // magic-mul
            int q = (u - r * 76) << 2;
            if (q < wc) {
                int row = min(r0 + r, HH - 1);       // tail dup is harmless
                float sx = fmaf((float)row + 0.5f, hstep, -0.5f);
                sx = fminf(fmaxf(sx, 0.0f), (float)hc - 1.0f);
                int bx = max(min((int)floorf(sx), hc - 2), 0);
                float fr = sx - (float)bx;
                float om = 1.0f - fr;
                int c = min(q, wc - 3);              // 16B read stays in row
                const float* p = img + (tlx + bx) * WW + tly + c;
                f4 a = *(const f4a*)p;               // source row bx
                f4 b = *(const f4a*)(p + WW);        // source row bx+1
                sV[r][c + 0] = fmaf(a.x, om, b.x * fr);
                sV[r][c + 1] = fmaf(a.y, om, b.y * fr);
                sV[r][c + 2] = fmaf(a.z, om, b.z * fr);
                sV[r][c + 3] = fmaf(a.w, om, b.w * fr);
            }
        }
    }
    __syncthreads();

    // Output: col j per thread; block writes ONE contiguous ~14.3 KB span
    // (RPB adjacent rows of one channel plane).
    int pbase = sgc * HW;                // element index base (< 2^31)
    for (int j = t; j < WW; j += NT) {
        float sy = fmaf((float)j + 0.5f, (float)wc * INV299, -0.5f);
        sy = fminf(fmaxf(sy, 0.0f), (float)wc - 1.0f);
        int by = max(min((int)floorf(sy), wc - 2), 0);
        float fy   = sy - (float)by;
        float omfy = 1.0f - fy;

        #pragma unroll
        for (int r = 0; r < RPB; ++r) {
            int row = r0 + r;
            if (row < HH) {                          // uniform guard (tail)
                out[pbase + row * WW + j] =
                    fmaf(sV[r][by], omfy, sV[r][by + 1] * fy);
            }
        }
    }
}

extern "C" void kernel_launch(void* const* d_in, const int* in_sizes, int n_in,
                              void* d_out, int out_size, void* d_ws, size_t ws_size,
                              hipStream_t stream) {
    const float* x = (const float*)d_in[0];
    const int*   f = (const int*)d_in[1];
    float* out = (float*)d_out;

    int S = in_sizes[0] / (3 * HW);   // 32
    int G = in_sizes[1] / (S * 4);    // 16

    dim3 grid((unsigned)(S * G * 3 * CHUNKS));  // 38400 = 8 * 4800
    dim3 block(NT);
    crop_resize_kernel<<<grid, block, 0, stream>>>(x, f, out, G);
}